// Round 2
// baseline (251.992 us; speedup 1.0000x reference)
//
#include <hip/hip_runtime.h>
#include <stdint.h>
#include <stddef.h>

// Problem constants (B=2,S=2048,D=1024,H=16,HD=64)
#define SCALE_LOG2E 11.541560327111707f   // 8 * log2(e): folded into Q projection
#define E8 4194304                        // 4096*1024 plane (elements)
#define M1 1048576                        // 1024*1024 plane
#define NROW 65536                        // B*H*S rows

typedef __attribute__((ext_vector_type(8))) _Float16 f16x8;
typedef __attribute__((ext_vector_type(4))) _Float16 f16x4;
typedef __attribute__((ext_vector_type(4))) float f32x4;

#if __has_builtin(__builtin_amdgcn_exp2f)
#define EXP2F(x) __builtin_amdgcn_exp2f(x)
#else
#define EXP2F(x) exp2f(x)
#endif

__device__ __forceinline__ f32x4 mfma_f16(f16x8 a, f16x8 b, f32x4 c) {
  return __builtin_amdgcn_mfma_f32_16x16x32_f16(a, b, c, 0, 0, 0);
}

// Legacy 16x16x16 f16 MFMA: B-operand layout k = qd*4 + j matches the
// 16x16 C-layout row = qd*4 + r, so QK^T scores feed PV directly (no LDS, no shuffles).
__device__ __forceinline__ f32x4 mfma16_f16(f16x4 a, f16x4 b, f32x4 c) {
  return __builtin_amdgcn_mfma_f32_16x16x16f16(a, b, c, 0, 0, 0);
}

// async global->LDS, 16B per lane. LDS dest is wave-uniform base + lane*16.
__device__ __forceinline__ void async16(const void* g, void* lds) {
  __builtin_amdgcn_global_load_lds(
      (const __attribute__((address_space(1))) unsigned int*)g,
      (__attribute__((address_space(3))) unsigned int*)lds, 16, 0, 0);
}

// ---------------- merged fp32 -> fp16 conversion (all 7 tensors) ----------------
__global__ void prep_all(const float* __restrict__ q, const float* __restrict__ k,
                         const float* __restrict__ v,
                         const float* __restrict__ wq, const float* __restrict__ wk,
                         const float* __restrict__ wv, const float* __restrict__ wo,
                         _Float16* __restrict__ Xf, _Float16* __restrict__ Wf) {
  const int gid = blockIdx.x;
  const float* src;
  _Float16* dst;
  int i;
  if (gid < 12288) {
    const int z = gid >> 12;
    src = (z == 0) ? q : (z == 1) ? k : v;
    dst = Xf + (size_t)z * E8;
    i = (gid & 4095) * 256 + threadIdx.x;
  } else {
    const int g2 = gid - 12288;
    const int z = g2 >> 10;
    src = (z == 0) ? wq : (z == 1) ? wk : (z == 2) ? wv : wo;
    dst = Wf + (size_t)z * M1;
    i = (g2 & 1023) * 256 + threadIdx.x;
  }
  float4 x = ((const float4*)src)[i];
  f16x4 h = {(_Float16)x.x, (_Float16)x.y, (_Float16)x.z, (_Float16)x.w};
  ((f16x4*)dst)[i] = h;
}

// ---------------- merged Q/K/V projection: fp16 GEMM, LDS double-buffered ----------------
// z=0: Q (bias bq, *SCALE_LOG2E) -> [B,H,S,HD] at Of
// z=1: K (bias bk)               -> [B,H,S,HD] at Of+E8
// z=2: V (bias bv)               -> V^T [B,H,HD,S] at Of+2*E8
__global__ __launch_bounds__(256, 3) void gemm_qkv(
    const _Float16* __restrict__ Xf,    // 3 planes stride E8
    const _Float16* __restrict__ Wf,    // 4 planes stride M1
    const float* __restrict__ bq, const float* __restrict__ bk,
    const float* __restrict__ bv,
    _Float16* __restrict__ Of)
{
  __shared__ _Float16 SMEM[16384];      // staging dbuf (2x4096 A + 2x4096 B) / epilogue Ct
  _Float16* LA = SMEM;                  // [2][4096]
  _Float16* LB = SMEM + 8192;           // [2][4096]
  const int z = blockIdx.z;
  const int tid = threadIdx.x;
  const int lane = tid & 63;
  const int wv = tid >> 6;
  const int wm = wv >> 1, wn = wv & 1;
  const int rl = lane & 15, qd = lane >> 4;
  const int m0 = blockIdx.y * 128, n0 = blockIdx.x * 128;

  const _Float16* A0 = Xf + (size_t)z * E8;
  const _Float16* W0 = Wf + (size_t)z * M1;
  const float* bias = (z == 0) ? bq : (z == 1) ? bk : bv;

  f32x4 acc[4][4];
#pragma unroll
  for (int i = 0; i < 4; i++)
#pragma unroll
    for (int j = 0; j < 4; j++) acc[i][j] = f32x4{0.f, 0.f, 0.f, 0.f};

  const int srow = wv * 32 + (lane >> 2);
  const int scol = (lane & 3) * 8;

  auto stage = [&](int k0, int buf) {
    const _Float16* ga = A0 + (size_t)(m0 + srow) * 1024 + k0 + scol;
    async16(ga, &LA[buf * 4096 + wv * 1024]);
    async16(ga + 16 * 1024, &LA[buf * 4096 + wv * 1024 + 512]);
    const _Float16* gb = W0 + (size_t)(n0 + srow) * 1024 + k0 + scol;
    async16(gb, &LB[buf * 4096 + wv * 1024]);
    async16(gb + 16 * 1024, &LB[buf * 4096 + wv * 1024 + 512]);
  };

  stage(0, 0);
  for (int t = 0; t < 32; t++) {
    const int buf = t & 1;
    __syncthreads();                          // DMA(t) drained; all done with buf^1
    if (t + 1 < 32) stage((t + 1) * 32, buf ^ 1);
    f16x8 af[4], bfr[4];
#pragma unroll
    for (int i = 0; i < 4; i++) af[i] = *(const f16x8*)&LA[buf * 4096 + (wm * 64 + i * 16 + rl) * 32 + qd * 8];
#pragma unroll
    for (int j = 0; j < 4; j++) bfr[j] = *(const f16x8*)&LB[buf * 4096 + (wn * 64 + j * 16 + rl) * 32 + qd * 8];
#pragma unroll
    for (int i = 0; i < 4; i++)
#pragma unroll
      for (int j = 0; j < 4; j++) acc[i][j] = mfma_f16(af[i], bfr[j], acc[i][j]);
  }

  if (z == 2) {
    // V^T epilogue: Vt[b,h,e,s], 4 contiguous s per store
#pragma unroll
    for (int j = 0; j < 4; j++) {
      const int nn = n0 + wn * 64 + j * 16 + rl;
      const float bj = bias[nn];
      const int hh = nn >> 6, e = nn & 63;
#pragma unroll
      for (int i = 0; i < 4; i++) {
        const int mm = m0 + wm * 64 + i * 16 + qd * 4;
        const int b = mm >> 11, s = mm & 2047;
        f16x4 pk = {(_Float16)(acc[i][j][0] + bj), (_Float16)(acc[i][j][1] + bj),
                    (_Float16)(acc[i][j][2] + bj), (_Float16)(acc[i][j][3] + bj)};
        *(f16x4*)(Of + 2 * (size_t)E8 + (((size_t)((b * 16 + hh) * 64 + e)) << 11) + s) = pk;
      }
    }
  } else {
    // LDS-transposed coalesced epilogue: Ct[128][128] with qd-xor column swizzle
    const float scl = (z == 0) ? SCALE_LOG2E : 1.0f;
    _Float16* base = Of + (size_t)z * E8;
    __syncthreads();                          // staging LDS now free
#pragma unroll
    for (int j = 0; j < 4; j++) {
      const int nl = wn * 64 + j * 16 + rl;
      const float bj = bias[n0 + nl];
#pragma unroll
      for (int i = 0; i < 4; i++) {
        const int ml = wm * 64 + i * 16 + qd * 4;
        const int np = nl ^ (qd << 4);        // (m>>2)&3 == qd here
#pragma unroll
        for (int r = 0; r < 4; r++)
          SMEM[(ml + r) * 128 + np] = (_Float16)((acc[i][j][r] + bj) * scl);
      }
    }
    __syncthreads();
#pragma unroll
    for (int it2 = 0; it2 < 8; it2++) {
      const int m = (it2 * 256 + tid) >> 4;   // 0..127
      const int col8 = (tid & 15) * 8;
      const int np = col8 ^ (((m >> 2) & 3) << 4);
      f16x8 vrow = *(const f16x8*)&SMEM[m * 128 + np];
      const int sg = m0 + m;
      const int b = sg >> 11, s = sg & 2047;
      const int nn = n0 + col8;
      const int hh = nn >> 6, e = nn & 63;
      *(f16x8*)(base + (((size_t)((b * 16 + hh) * 2048 + s)) << 6) + e) = vrow;
    }
  }
}

// ---------------- flash attention v8: conflict-free V slots + reg-staged V (T14) ----------------
// grid (16, 2, 32): x = q-block (128 rows), y = kv half (1024 keys), z = bh.
// Block 256 (4 waves x 32 q). S^T = K·Q^T; O^T = V^T·P^T via 16x16x16 (scores in-register).
// V LDS layout: 8B piece for (row, hc) lives at slot ((hc>>1)^(row&7))*2 + ((hc&1)^row3).
//   The row3 parity-xor puts rl bit 3 into the bank-slot index, so each 16-lane read
//   group hits 16 distinct 8B slots -> ds_read_b64 conflict-free (v7 was 2x conflicted:
//   SQ_LDS_BANK_CONFLICT = 4.19M). Half-swapped storage is impossible with async16
//   (contiguous src+dst), so V is reg-staged: global b128 load issued at top of iter
//   (T14 issue-early), ds_write_b128 after PV (write-late), half-swap is wave-uniform
//   (row&8 == wv&1) -> scalar branch. K stays on async16 (reads conflict-free).
// Softmax: p = exp2(sc - mnew) directly; T13 defer-max THR=8.
__global__ __launch_bounds__(256, 4) void attn_kernel(
    const _Float16* __restrict__ Qb,   // [B,H,S,HD], pre-scaled by 8*log2e
    const _Float16* __restrict__ Kb,   // [B,H,S,HD]
    const _Float16* __restrict__ Vt,   // [B,H,HD,S]
    float* __restrict__ Op,            // [2][NROW][64] f32 partial O^T (unnormalized)
    float2* __restrict__ ML)           // [2][NROW] (m, l)
{
  __shared__ _Float16 Ks[2][4096];     // dbuf [64 keys][64 d], xor-swizzled 16B chunks
  __shared__ _Float16 Vs[2][4096];     // dbuf [64 d][64 keys], 8B-slot swizzle (see above)
  const int tid = threadIdx.x;
  const int lane = tid & 63;
  const int wv = tid >> 6;
  const int rl = lane & 15, qd = lane >> 4;
  const int rl3 = (rl >> 3) & 1;
  const int bh = blockIdx.z;
  const int half = blockIdx.y;
  const int kvb = half * 1024;
  const int q0 = blockIdx.x * 128 + wv * 32;
  const int swp = __builtin_amdgcn_readfirstlane(wv & 1);  // == (stage row & 8)

  // Q as B-operand fragments [mt][kk]
  f16x8 qf[2][2];
#pragma unroll
  for (int mt = 0; mt < 2; mt++)
#pragma unroll
    for (int kk = 0; kk < 2; kk++)
      qf[mt][kk] = *(const f16x8*)(Qb + ((size_t)bh * 2048 + q0 + mt * 16 + rl) * 64 +
                                   kk * 32 + qd * 8);

  float m_[2] = {-1e30f, -1e30f}, l_[2] = {0.f, 0.f};  // l_ per-lane partial
  f32x4 o[2][4];
#pragma unroll
  for (int mt = 0; mt < 2; mt++)
#pragma unroll
    for (int jt = 0; jt < 4; jt++) o[mt][jt] = f32x4{0.f, 0.f, 0.f, 0.f};

  // K tile (8 KB) via async DMA, 16B-chunk xor swizzle
  auto stageK = [&](int kv, int buf) {
#pragma unroll
    for (int it = 0; it < 2; it++) {
      const int cI = it * 256 + tid;           // chunk index 0..511
      const int row = cI >> 3;
      const int c = (cI & 7) ^ (row & 7);
      async16(Kb + ((size_t)bh * 2048 + kv + row) * 64 + c * 8,
              &Ks[buf][(it * 256 + wv * 64) * 8]);
    }
  };
  // V tile: global b128 into regs (issue early)
  auto loadV = [&](int kv, f16x8* g) {
#pragma unroll
    for (int it = 0; it < 2; it++) {
      const int cI = it * 256 + tid;
      const int row = cI >> 3;                 // d-row 0..63
      g[it] = *(const f16x8*)(Vt + ((size_t)bh * 64 + row) * 2048 + kv + (cI & 7) * 8);
    }
  };
  // V tile: ds_write with chunk xor-swizzle + wave-uniform half-swap (write late)
  auto writeV = [&](int buf, const f16x8* g) {
#pragma unroll
    for (int it = 0; it < 2; it++) {
      const int cI = it * 256 + tid;
      const int row = cI >> 3;
      const int C = (cI & 7) ^ (row & 7);
      f16x8 w = g[it];
      if (swp) w = __builtin_shufflevector(w, w, 4, 5, 6, 7, 0, 1, 2, 3);
      *(f16x8*)&Vs[buf][row * 64 + C * 8] = w;
    }
  };

  f16x8 vg[2];
  stageK(kvb, 0);
  loadV(kvb, vg);
  writeV(0, vg);
  __syncthreads();                             // K DMA drained (vmcnt0) + V writes visible

  for (int t = 0; t < 16; t++) {
    const int buf = t & 1;
    if (t + 1 < 16) {
      loadV(kvb + (t + 1) * 64, vg);           // issue early: latency hides under QK+SM+PV
      stageK(kvb + (t + 1) * 64, buf ^ 1);
    }

    // ---- QK^T (S^T): sc[mt][nt]; key = nt*16 + qd*4 + r, q = q0 + mt*16 + rl ----
    f32x4 sc[2][4];
#pragma unroll
    for (int mt = 0; mt < 2; mt++)
#pragma unroll
      for (int nt = 0; nt < 4; nt++) sc[mt][nt] = f32x4{0.f, 0.f, 0.f, 0.f};
    __builtin_amdgcn_s_setprio(1);
#pragma unroll
    for (int nt = 0; nt < 4; nt++) {
      const int ro = (nt * 16 + rl) * 64;
#pragma unroll
      for (int kk = 0; kk < 2; kk++) {
        const int cc = (((kk * 4 + qd) ^ (rl & 7)) << 3);
        f16x8 kh = *(const f16x8*)&Ks[buf][ro + cc];
#pragma unroll
        for (int mt = 0; mt < 2; mt++)
          sc[mt][nt] = mfma_f16(kh, qf[mt][kk], sc[mt][nt]);
      }
    }
    __builtin_amdgcn_s_setprio(0);

    // ---- online softmax (exp2 domain), defer-max (THR=8), pack -> PV B-frags ----
    f16x4 pf[2][4];
#pragma unroll
    for (int mt = 0; mt < 2; mt++) {
      // tree max over this lane's 16 scores
      float a0 = fmaxf(fmaxf(sc[mt][0][0], sc[mt][0][1]), fmaxf(sc[mt][0][2], sc[mt][0][3]));
      float a1 = fmaxf(fmaxf(sc[mt][1][0], sc[mt][1][1]), fmaxf(sc[mt][1][2], sc[mt][1][3]));
      float a2 = fmaxf(fmaxf(sc[mt][2][0], sc[mt][2][1]), fmaxf(sc[mt][2][2], sc[mt][2][3]));
      float a3 = fmaxf(fmaxf(sc[mt][3][0], sc[mt][3][1]), fmaxf(sc[mt][3][2], sc[mt][3][3]));
      float mloc = fmaxf(fmaxf(a0, a1), fmaxf(a2, a3));
      // row max across the 4 qd lanes sharing rl
      float mx = fmaxf(mloc, __shfl_xor(mloc, 16));
      mx = fmaxf(mx, __shfl_xor(mx, 32));
      const float mold = m_[mt];
      float mnew = mold;
      if (__any(mx > mold + 8.f)) {            // T13: rescale only on real growth
        mnew = fmaxf(mold, mx);                // per-row (lanes with mx<=mold keep mold)
        const float al = EXP2F(mold - mnew);   // 1.0 where unchanged
        l_[mt] *= al;
#pragma unroll
        for (int jt = 0; jt < 4; jt++)
#pragma unroll
          for (int r = 0; r < 4; r++) o[mt][jt][r] *= al;
        m_[mt] = mnew;
      }
      // p bounded by 2^8 (defer threshold), fine in f16
      float sm = 0.f;
#pragma unroll
      for (int nt = 0; nt < 4; nt++) {
        const float p0 = EXP2F(sc[mt][nt][0] - mnew);
        const float p1 = EXP2F(sc[mt][nt][1] - mnew);
        const float p2 = EXP2F(sc[mt][nt][2] - mnew);
        const float p3 = EXP2F(sc[mt][nt][3] - mnew);
        sm += (p0 + p1) + (p2 + p3);
        pf[mt][nt] = f16x4{(_Float16)p0, (_Float16)p1, (_Float16)p2, (_Float16)p3};
      }
      l_[mt] += sm;
    }

    // ---- PV: O^T += V^T · P^T via 16x16x16; conflict-free 8B-slot reads ----
    __builtin_amdgcn_s_setprio(1);
    const int pbit = ((qd & 1) ^ rl3) << 2;    // slot parity (f16 units)
#pragma unroll
    for (int nt = 0; nt < 4; nt++) {
      const int cpart = (((nt * 2 + (qd >> 1)) ^ (rl & 7)) << 3);
#pragma unroll
      for (int jt = 0; jt < 4; jt++) {
        f16x4 vvv = *(const f16x4*)&Vs[buf][(jt * 16 + rl) * 64 + cpart + pbit];
        o[0][jt] = mfma16_f16(vvv, pf[0][nt], o[0][jt]);
        o[1][jt] = mfma16_f16(vvv, pf[1][nt], o[1][jt]);
      }
    }
    __builtin_amdgcn_s_setprio(0);

    if (t + 1 < 16) writeV(buf ^ 1, vg);       // write late: vmcnt wait lands here
    __syncthreads();                           // publishes Ks DMA + Vs writes for t+1
  }

  // epilogue: write partials (unnormalized). lane holds d = jt*16 + qd*4 + r.
#pragma unroll
  for (int mt = 0; mt < 2; mt++) {
    float lt = l_[mt] + __shfl_xor(l_[mt], 16);
    lt += __shfl_xor(lt, 32);
    const size_t row = (size_t)bh * 2048 + q0 + mt * 16 + rl;
    float* op = Op + ((size_t)half * NROW + row) * 64;
#pragma unroll
    for (int jt = 0; jt < 4; jt++)
      *(f32x4*)(op + jt * 16 + qd * 4) = o[mt][jt];
    if (qd == 0) ML[(size_t)half * NROW + row] = make_float2(m_[mt], lt);
  }
}

// ---------------- merge the two KV halves ----------------
// block 256 = 16 rows x 16 threads; thread handles 4 d.
__global__ void merge_kernel(const float* __restrict__ Op,
                             const float2* __restrict__ ML,
                             _Float16* __restrict__ Xo) {
  const int t = threadIdx.x;
  const int row = blockIdx.x * 16 + (t >> 4);
  const int d0 = (t & 15) * 4;
  const float2 ml1 = ML[row];
  const float2 ml2 = ML[NROW + row];
  const float m = fmaxf(ml1.x, ml2.x);
  const float w1 = EXP2F(ml1.x - m), w2 = EXP2F(ml2.x - m);
  const float inv = 1.0f / (ml1.y * w1 + ml2.y * w2);
  const float4 o1 = *(const float4*)(Op + (size_t)row * 64 + d0);
  const float4 o2 = *(const float4*)(Op + (size_t)NROW * 64 + (size_t)row * 64 + d0);
  const int bh = row >> 11, q = row & 2047;
  const int b = bh >> 4, hh = bh & 15;
  f16x4 pk = {(_Float16)((o1.x * w1 + o2.x * w2) * inv),
              (_Float16)((o1.y * w1 + o2.y * w2) * inv),
              (_Float16)((o1.z * w1 + o2.z * w2) * inv),
              (_Float16)((o1.w * w1 + o2.w * w2) * inv)};
  *(f16x4*)(Xo + ((size_t)(b * 2048 + q)) * 1024 + hh * 64 + d0) = pk;
}

// ---------------- output projection: 64x128 tile, dbuf, fp32 out ----------------
__global__ __launch_bounds__(256, 2) void gemm_out(
    const _Float16* __restrict__ A0,
    const _Float16* __restrict__ W0,
    const float* __restrict__ bias,
    float* __restrict__ out)
{
  __shared__ _Float16 LA[2][2048];   // 64 x 32
  __shared__ _Float16 LB[2][4096];   // 128 x 32
  const int tid = threadIdx.x;
  const int lane = tid & 63;
  const int wv = tid >> 6;
  const int wm = wv >> 1, wn = wv & 1;
  const int rl = lane & 15, qd = lane >> 4;
  const int m0 = blockIdx.y * 64, n0 = blockIdx.x * 128;

  f32x4 acc[2][4];
#pragma unroll
  for (int i = 0; i < 2; i++)
#pragma unroll
    for (int j = 0; j < 4; j++) acc[i][j] = f32x4{0.f, 0.f, 0.f, 0.f};

  auto stage = [&](int k0, int buf) {
    {  // A: 256 chunks, 1 per thread
      const int row = tid >> 2, c = tid & 3;
      async16(A0 + (size_t)(m0 + row) * 1024 + k0 + c * 8, &LA[buf][wv * 512]);
    }
#pragma unroll
    for (int it = 0; it < 2; it++) {  // B: 512 chunks, 2 per thread
      const int cI = it * 256 + tid;
      const int row = cI >> 2, c = cI & 3;
      async16(W0 + (size_t)(n0 + row) * 1024 + k0 + c * 8,
              &LB[buf][it * 2048 + wv * 512]);
    }
  };

  stage(0, 0);
  for (int t = 0; t < 32; t++) {
    const int buf = t & 1;
    __syncthreads();
    if (t + 1 < 32) stage((t + 1) * 32, buf ^ 1);
    f16x8 af[2], bfr[4];
#pragma unroll
    for (int i = 0; i < 2; i++) af[i] = *(const f16x8*)&LA[buf][(wm * 32 + i * 16 + rl) * 32 + qd * 8];
#pragma unroll
    for (int j = 0; j < 4; j++) bfr[j] = *(const f16x8*)&LB[buf][(wn * 64 + j * 16 + rl) * 32 + qd * 8];
#pragma unroll
    for (int i = 0; i < 2; i++)
#pragma unroll
      for (int j = 0; j < 4; j++) acc[i][j] = mfma_f16(af[i], bfr[j], acc[i][j]);
  }

#pragma unroll
  for (int j = 0; j < 4; j++) {
    const int nn = n0 + wn * 64 + j * 16 + rl;
    const float bj = bias[nn];
#pragma unroll
    for (int i = 0; i < 2; i++) {
      const int mm = m0 + wm * 32 + i * 16 + qd * 4;
#pragma unroll
      for (int r = 0; r < 4; r++)
        out[(size_t)(mm + r) * 1024 + nn] = acc[i][j][r] + bj;
    }
  }
}

// ---------------- launch ----------------
extern "C" void kernel_launch(void* const* d_in, const int* in_sizes, int n_in,
                              void* d_out, int out_size, void* d_ws, size_t ws_size,
                              hipStream_t stream) {
  const float* query = (const float*)d_in[0];
  const float* key   = (const float*)d_in[1];
  const float* value = (const float*)d_in[2];
  const float* Wq = (const float*)d_in[3];
  const float* bq = (const float*)d_in[4];
  const float* Wk = (const float*)d_in[5];
  const float* bk = (const float*)d_in[6];
  const float* Wv = (const float*)d_in[7];
  const float* bv = (const float*)d_in[8];
  const float* Wo = (const float*)d_in[9];
  const float* bo = (const float*)d_in[10];

  // workspace: f16 region 67 MB + f32 partials 34.6 MB
  _Float16* ws = (_Float16*)d_ws;
  _Float16* Xf = ws;                          // 3*E8: query,key,value fp16
  _Float16* Wf = ws + 3 * (size_t)E8;         // 4*M1: Wq,Wk,Wv,Wo fp16
  _Float16* Qh = Wf + 4 * (size_t)M1;         // E8 [B,H,S,HD] (pre-scaled)
  _Float16* Kh = Qh + (size_t)E8;             // E8 [B,H,S,HD]
  _Float16* Vt = Kh + (size_t)E8;             // E8 [B,H,HD,S]
  _Float16* Xa = Vt + (size_t)E8;             // E8 [B,S,D]
  float*    Op = (float*)(Xa + (size_t)E8);   // [2][NROW][64] f32
  float2*   ML = (float2*)(Op + 2 * (size_t)NROW * 64);  // [2][NROW]

  prep_all<<<16384, 256, 0, stream>>>(query, key, value, Wq, Wk, Wv, Wo, Xf, Wf);
  gemm_qkv<<<dim3(8, 32, 3), 256, 0, stream>>>(Xf, Wf, bq, bk, bv, Qh);
  attn_kernel<<<dim3(16, 2, 32), 256, 0, stream>>>(Qh, Kh, Vt, Op, ML);
  merge_kernel<<<4096, 256, 0, stream>>>(Op, ML, Xa);
  gemm_out<<<dim3(8, 64), 256, 0, stream>>>(Xa, Wf + 3 * (size_t)M1, bo, (float*)d_out);
}

// Round 3
// 248.491 us; speedup vs baseline: 1.0141x; 1.0141x over previous
//
#include <hip/hip_runtime.h>
#include <stdint.h>
#include <stddef.h>

// Problem constants (B=2,S=2048,D=1024,H=16,HD=64)
#define SCALE_LOG2E 11.541560327111707f   // 8 * log2(e): folded into Q projection
#define E8 4194304                        // 4096*1024 plane (elements)
#define M1 1048576                        // 1024*1024 plane
#define NROW 65536                        // B*H*S rows

typedef __attribute__((ext_vector_type(8))) _Float16 f16x8;
typedef __attribute__((ext_vector_type(4))) _Float16 f16x4;
typedef __attribute__((ext_vector_type(4))) float f32x4;

#if __has_builtin(__builtin_amdgcn_exp2f)
#define EXP2F(x) __builtin_amdgcn_exp2f(x)
#else
#define EXP2F(x) exp2f(x)
#endif

__device__ __forceinline__ f32x4 mfma_f16(f16x8 a, f16x8 b, f32x4 c) {
  return __builtin_amdgcn_mfma_f32_16x16x32_f16(a, b, c, 0, 0, 0);
}

// Legacy 16x16x16 f16 MFMA: B-operand layout k = qd*4 + j matches the
// 16x16 C-layout row = qd*4 + r, so QK^T scores feed PV directly (no LDS, no shuffles).
__device__ __forceinline__ f32x4 mfma16_f16(f16x4 a, f16x4 b, f32x4 c) {
  return __builtin_amdgcn_mfma_f32_16x16x16f16(a, b, c, 0, 0, 0);
}

// async global->LDS, 16B per lane. LDS dest is wave-uniform base + lane*16.
__device__ __forceinline__ void async16(const void* g, void* lds) {
  __builtin_amdgcn_global_load_lds(
      (const __attribute__((address_space(1))) unsigned int*)g,
      (__attribute__((address_space(3))) unsigned int*)lds, 16, 0, 0);
}

// ---------------- merged fp32 -> fp16 conversion (all 7 tensors) ----------------
__global__ void prep_all(const float* __restrict__ q, const float* __restrict__ k,
                         const float* __restrict__ v,
                         const float* __restrict__ wq, const float* __restrict__ wk,
                         const float* __restrict__ wv, const float* __restrict__ wo,
                         _Float16* __restrict__ Xf, _Float16* __restrict__ Wf) {
  const int gid = blockIdx.x;
  const float* src;
  _Float16* dst;
  int i;
  if (gid < 12288) {
    const int z = gid >> 12;
    src = (z == 0) ? q : (z == 1) ? k : v;
    dst = Xf + (size_t)z * E8;
    i = (gid & 4095) * 256 + threadIdx.x;
  } else {
    const int g2 = gid - 12288;
    const int z = g2 >> 10;
    src = (z == 0) ? wq : (z == 1) ? wk : (z == 2) ? wv : wo;
    dst = Wf + (size_t)z * M1;
    i = (g2 & 1023) * 256 + threadIdx.x;
  }
  float4 x = ((const float4*)src)[i];
  f16x4 h = {(_Float16)x.x, (_Float16)x.y, (_Float16)x.z, (_Float16)x.w};
  ((f16x4*)dst)[i] = h;
}

// ---------------- merged Q/K/V projection: fp16 GEMM, LDS double-buffered ----------------
// z=0: Q (bias bq, *SCALE_LOG2E) -> [B,H,S,HD] at Of
// z=1: K (bias bk)               -> [B,H,S,HD] at Of+E8
// z=2: V (bias bv)               -> V^T [B,H,HD,S] at Of+2*E8
__global__ __launch_bounds__(256, 3) void gemm_qkv(
    const _Float16* __restrict__ Xf,    // 3 planes stride E8
    const _Float16* __restrict__ Wf,    // 4 planes stride M1
    const float* __restrict__ bq, const float* __restrict__ bk,
    const float* __restrict__ bv,
    _Float16* __restrict__ Of)
{
  __shared__ _Float16 SMEM[16384];      // staging dbuf (2x4096 A + 2x4096 B) / epilogue Ct
  _Float16* LA = SMEM;                  // [2][4096]
  _Float16* LB = SMEM + 8192;           // [2][4096]
  const int z = blockIdx.z;
  const int tid = threadIdx.x;
  const int lane = tid & 63;
  const int wv = tid >> 6;
  const int wm = wv >> 1, wn = wv & 1;
  const int rl = lane & 15, qd = lane >> 4;
  const int m0 = blockIdx.y * 128, n0 = blockIdx.x * 128;

  const _Float16* A0 = Xf + (size_t)z * E8;
  const _Float16* W0 = Wf + (size_t)z * M1;
  const float* bias = (z == 0) ? bq : (z == 1) ? bk : bv;

  f32x4 acc[4][4];
#pragma unroll
  for (int i = 0; i < 4; i++)
#pragma unroll
    for (int j = 0; j < 4; j++) acc[i][j] = f32x4{0.f, 0.f, 0.f, 0.f};

  const int srow = wv * 32 + (lane >> 2);
  const int scol = (lane & 3) * 8;

  auto stage = [&](int k0, int buf) {
    const _Float16* ga = A0 + (size_t)(m0 + srow) * 1024 + k0 + scol;
    async16(ga, &LA[buf * 4096 + wv * 1024]);
    async16(ga + 16 * 1024, &LA[buf * 4096 + wv * 1024 + 512]);
    const _Float16* gb = W0 + (size_t)(n0 + srow) * 1024 + k0 + scol;
    async16(gb, &LB[buf * 4096 + wv * 1024]);
    async16(gb + 16 * 1024, &LB[buf * 4096 + wv * 1024 + 512]);
  };

  stage(0, 0);
  for (int t = 0; t < 32; t++) {
    const int buf = t & 1;
    __syncthreads();                          // DMA(t) drained; all done with buf^1
    if (t + 1 < 32) stage((t + 1) * 32, buf ^ 1);
    f16x8 af[4], bfr[4];
#pragma unroll
    for (int i = 0; i < 4; i++) af[i] = *(const f16x8*)&LA[buf * 4096 + (wm * 64 + i * 16 + rl) * 32 + qd * 8];
#pragma unroll
    for (int j = 0; j < 4; j++) bfr[j] = *(const f16x8*)&LB[buf * 4096 + (wn * 64 + j * 16 + rl) * 32 + qd * 8];
#pragma unroll
    for (int i = 0; i < 4; i++)
#pragma unroll
      for (int j = 0; j < 4; j++) acc[i][j] = mfma_f16(af[i], bfr[j], acc[i][j]);
  }

  if (z == 2) {
    // V^T epilogue: Vt[b,h,e,s], 4 contiguous s per store
#pragma unroll
    for (int j = 0; j < 4; j++) {
      const int nn = n0 + wn * 64 + j * 16 + rl;
      const float bj = bias[nn];
      const int hh = nn >> 6, e = nn & 63;
#pragma unroll
      for (int i = 0; i < 4; i++) {
        const int mm = m0 + wm * 64 + i * 16 + qd * 4;
        const int b = mm >> 11, s = mm & 2047;
        f16x4 pk = {(_Float16)(acc[i][j][0] + bj), (_Float16)(acc[i][j][1] + bj),
                    (_Float16)(acc[i][j][2] + bj), (_Float16)(acc[i][j][3] + bj)};
        *(f16x4*)(Of + 2 * (size_t)E8 + (((size_t)((b * 16 + hh) * 64 + e)) << 11) + s) = pk;
      }
    }
  } else {
    // LDS-transposed coalesced epilogue: Ct[128][128] with qd-xor column swizzle
    const float scl = (z == 0) ? SCALE_LOG2E : 1.0f;
    _Float16* base = Of + (size_t)z * E8;
    __syncthreads();                          // staging LDS now free
#pragma unroll
    for (int j = 0; j < 4; j++) {
      const int nl = wn * 64 + j * 16 + rl;
      const float bj = bias[n0 + nl];
#pragma unroll
      for (int i = 0; i < 4; i++) {
        const int ml = wm * 64 + i * 16 + qd * 4;
        const int np = nl ^ (qd << 4);        // (m>>2)&3 == qd here
#pragma unroll
        for (int r = 0; r < 4; r++)
          SMEM[(ml + r) * 128 + np] = (_Float16)((acc[i][j][r] + bj) * scl);
      }
    }
    __syncthreads();
#pragma unroll
    for (int it2 = 0; it2 < 8; it2++) {
      const int m = (it2 * 256 + tid) >> 4;   // 0..127
      const int col8 = (tid & 15) * 8;
      const int np = col8 ^ (((m >> 2) & 3) << 4);
      f16x8 vrow = *(const f16x8*)&SMEM[m * 128 + np];
      const int sg = m0 + m;
      const int b = sg >> 11, s = sg & 2047;
      const int nn = n0 + col8;
      const int hh = nn >> 6, e = nn & 63;
      *(f16x8*)(base + (((size_t)((b * 16 + hh) * 2048 + s)) << 6) + e) = vrow;
    }
  }
}

// ---------------- flash attention v9: full-occupancy (mt=1, KVBLK=32, 16KB LDS) ----------------
// grid (32, 2, 32): x = q-block (64 rows), y = kv half (1024 keys), z = bh.
// 2048 blocks = 8 blocks/CU = 32 waves/CU (100% theoretical occupancy; LDS 8x16KB=128KB,
// VGPR forced <=64 via launch_bounds(256,8)). v8 was latency-bound at 31% occupancy
// (conflict fix was counter-confirmed but off the critical path).
// Block 256 (4 waves x 16 q each). S^T = K·Q^T; O^T = V^T·P^T via 16x16x16 in-register P.
// V LDS layout [64 d][32 keys]: 8B piece hc = nt*4+qd of row lives at slot hc ^ ((row>>1)&7)
//   -> each 16-lane b64 read group hits 16 distinct bank-pairs (even/odd rows each bijective),
//   conflict-free. Write side: 16B chunk c -> pos c ^ ((row>>2)&3), halves swapped iff row&2
//   (per-lane cndmask; reg-staged V since async16 can't half-swap). K stays on async16.
// Softmax: p = exp2(sc - mnew) direct; T13 defer-max THR=8.
__global__ __launch_bounds__(256, 8) void attn_kernel(
    const _Float16* __restrict__ Qb,   // [B,H,S,HD], pre-scaled by 8*log2e
    const _Float16* __restrict__ Kb,   // [B,H,S,HD]
    const _Float16* __restrict__ Vt,   // [B,H,HD,S]
    float* __restrict__ Op,            // [2][NROW][64] f32 partial O^T (unnormalized)
    float2* __restrict__ ML)           // [2][NROW] (m, l)
{
  __shared__ _Float16 Ks[2][2048];     // dbuf [32 keys][64 d], xor-swizzled 16B chunks
  __shared__ _Float16 Vs[2][2048];     // dbuf [64 d][32 keys], 8B-slot swizzle (see above)
  const int tid = threadIdx.x;
  const int lane = tid & 63;
  const int wv = tid >> 6;
  const int rl = lane & 15, qd = lane >> 4;
  const int bh = blockIdx.z;
  const int half = blockIdx.y;
  const int kvb = half * 1024;
  const int q0 = blockIdx.x * 64 + wv * 16;

  // Q as B-operand fragments [kk]
  f16x8 qf[2];
#pragma unroll
  for (int kk = 0; kk < 2; kk++)
    qf[kk] = *(const f16x8*)(Qb + ((size_t)bh * 2048 + q0 + rl) * 64 + kk * 32 + qd * 8);

  float m_ = -1e30f, l_ = 0.f;         // l_ per-lane partial
  f32x4 o[4];
#pragma unroll
  for (int jt = 0; jt < 4; jt++) o[jt] = f32x4{0.f, 0.f, 0.f, 0.f};

  // K tile (4 KB) via async DMA, 16B-chunk xor swizzle: chunk cI=tid -> row=tid>>3,
  // src chunk (tid&7)^(row&7); LDS linear => read swizzle cc = (kc ^ (rl&7))<<3.
  auto stageK = [&](int kv, int buf) {
    const int row = tid >> 3;
    const int c = (tid & 7) ^ (row & 7);
    async16(Kb + ((size_t)bh * 2048 + kv + row) * 64 + c * 8, &Ks[buf][wv * 512]);
  };
  // V tile (4 KB): global b128 into regs (issue early). chunk cI=tid: row=tid>>2, c=tid&3.
  auto loadV = [&](int kv, f16x8& g) {
    const int row = tid >> 2;
    g = *(const f16x8*)(Vt + ((size_t)bh * 64 + row) * 2048 + kv + (tid & 3) * 8);
  };
  // V tile: ds_write at chunk pos c ^ ((row>>2)&3), halves swapped iff row&2 (write late).
  auto writeV = [&](int buf, f16x8 g) {
    const int row = tid >> 2;
    const int cpos = (tid & 3) ^ ((row >> 2) & 3);
    f16x8 w = (row & 2) ? __builtin_shufflevector(g, g, 4, 5, 6, 7, 0, 1, 2, 3) : g;
    *(f16x8*)&Vs[buf][row * 32 + cpos * 8] = w;
  };

  f16x8 vg;
  stageK(kvb, 0);
  loadV(kvb, vg);
  writeV(0, vg);
  __syncthreads();                             // K DMA drained (vmcnt0) + V writes visible

  for (int t = 0; t < 32; t++) {
    const int buf = t & 1;
    if (t + 1 < 32) {
      loadV(kvb + (t + 1) * 32, vg);           // issue early: latency hides under QK+SM+PV
      stageK(kvb + (t + 1) * 32, buf ^ 1);
    }

    // ---- QK^T (S^T): sc[nt]; key = nt*16 + qd*4 + r, q = q0 + rl ----
    f32x4 sc[2];
#pragma unroll
    for (int nt = 0; nt < 2; nt++) sc[nt] = f32x4{0.f, 0.f, 0.f, 0.f};
    __builtin_amdgcn_s_setprio(1);
#pragma unroll
    for (int nt = 0; nt < 2; nt++) {
      const int ro = (nt * 16 + rl) * 64;
#pragma unroll
      for (int kk = 0; kk < 2; kk++) {
        const int cc = (((kk * 4 + qd) ^ (rl & 7)) << 3);
        f16x8 kh = *(const f16x8*)&Ks[buf][ro + cc];
        sc[nt] = mfma_f16(kh, qf[kk], sc[nt]);
      }
    }
    __builtin_amdgcn_s_setprio(0);

    // ---- online softmax (exp2 domain), defer-max (THR=8), pack -> PV B-frags ----
    f16x4 pf[2];
    {
      float a0 = fmaxf(fmaxf(sc[0][0], sc[0][1]), fmaxf(sc[0][2], sc[0][3]));
      float a1 = fmaxf(fmaxf(sc[1][0], sc[1][1]), fmaxf(sc[1][2], sc[1][3]));
      float mloc = fmaxf(a0, a1);
      // row max across the 4 qd lanes sharing rl
      float mx = fmaxf(mloc, __shfl_xor(mloc, 16));
      mx = fmaxf(mx, __shfl_xor(mx, 32));
      const float mold = m_;
      float mnew = mold;
      if (__any(mx > mold + 8.f)) {            // T13: rescale only on real growth
        mnew = fmaxf(mold, mx);                // per-row (rows with mx<=mold keep mold)
        const float al = EXP2F(mold - mnew);   // 1.0 where unchanged
        l_ *= al;
#pragma unroll
        for (int jt = 0; jt < 4; jt++)
#pragma unroll
          for (int r = 0; r < 4; r++) o[jt][r] *= al;
        m_ = mnew;
      }
      // p bounded by 2^8 (defer threshold), fine in f16
      float sm = 0.f;
#pragma unroll
      for (int nt = 0; nt < 2; nt++) {
        const float p0 = EXP2F(sc[nt][0] - mnew);
        const float p1 = EXP2F(sc[nt][1] - mnew);
        const float p2 = EXP2F(sc[nt][2] - mnew);
        const float p3 = EXP2F(sc[nt][3] - mnew);
        sm += (p0 + p1) + (p2 + p3);
        pf[nt] = f16x4{(_Float16)p0, (_Float16)p1, (_Float16)p2, (_Float16)p3};
      }
      l_ += sm;
    }

    // ---- PV: O^T += V^T · P^T via 16x16x16; conflict-free 8B-slot reads ----
    __builtin_amdgcn_s_setprio(1);
    const int rg = (rl >> 1) & 7;              // ((jt*16+rl)>>1)&7 == (rl>>1)&7
#pragma unroll
    for (int nt = 0; nt < 2; nt++) {
      const int sl = ((nt * 4 + qd) ^ rg) << 2;  // slot*4 f16 units
#pragma unroll
      for (int jt = 0; jt < 4; jt++) {
        f16x4 vvv = *(const f16x4*)&Vs[buf][(jt * 16 + rl) * 32 + sl];
        o[jt] = mfma16_f16(vvv, pf[nt], o[jt]);
      }
    }
    __builtin_amdgcn_s_setprio(0);

    if (t + 1 < 32) writeV(buf ^ 1, vg);       // write late: vmcnt wait lands here
    __syncthreads();                           // publishes Ks DMA + Vs writes for t+1
  }

  // epilogue: write partials (unnormalized). lane holds d = jt*16 + qd*4 + r for row q0+rl.
  {
    float lt = l_ + __shfl_xor(l_, 16);
    lt += __shfl_xor(lt, 32);
    const size_t row = (size_t)bh * 2048 + q0 + rl;
    float* op = Op + ((size_t)half * NROW + row) * 64;
#pragma unroll
    for (int jt = 0; jt < 4; jt++)
      *(f32x4*)(op + jt * 16 + qd * 4) = o[jt];
    if (qd == 0) ML[(size_t)half * NROW + row] = make_float2(m_, lt);
  }
}

// ---------------- merge the two KV halves ----------------
// block 256 = 16 rows x 16 threads; thread handles 4 d.
__global__ void merge_kernel(const float* __restrict__ Op,
                             const float2* __restrict__ ML,
                             _Float16* __restrict__ Xo) {
  const int t = threadIdx.x;
  const int row = blockIdx.x * 16 + (t >> 4);
  const int d0 = (t & 15) * 4;
  const float2 ml1 = ML[row];
  const float2 ml2 = ML[NROW + row];
  const float m = fmaxf(ml1.x, ml2.x);
  const float w1 = EXP2F(ml1.x - m), w2 = EXP2F(ml2.x - m);
  const float inv = 1.0f / (ml1.y * w1 + ml2.y * w2);
  const float4 o1 = *(const float4*)(Op + (size_t)row * 64 + d0);
  const float4 o2 = *(const float4*)(Op + (size_t)NROW * 64 + (size_t)row * 64 + d0);
  const int bh = row >> 11, q = row & 2047;
  const int b = bh >> 4, hh = bh & 15;
  f16x4 pk = {(_Float16)((o1.x * w1 + o2.x * w2) * inv),
              (_Float16)((o1.y * w1 + o2.y * w2) * inv),
              (_Float16)((o1.z * w1 + o2.z * w2) * inv),
              (_Float16)((o1.w * w1 + o2.w * w2) * inv)};
  *(f16x4*)(Xo + ((size_t)(b * 2048 + q)) * 1024 + hh * 64 + d0) = pk;
}

// ---------------- output projection: 64x128 tile, dbuf, fp32 out ----------------
__global__ __launch_bounds__(256, 2) void gemm_out(
    const _Float16* __restrict__ A0,
    const _Float16* __restrict__ W0,
    const float* __restrict__ bias,
    float* __restrict__ out)
{
  __shared__ _Float16 LA[2][2048];   // 64 x 32
  __shared__ _Float16 LB[2][4096];   // 128 x 32
  const int tid = threadIdx.x;
  const int lane = tid & 63;
  const int wv = tid >> 6;
  const int wm = wv >> 1, wn = wv & 1;
  const int rl = lane & 15, qd = lane >> 4;
  const int m0 = blockIdx.y * 64, n0 = blockIdx.x * 128;

  f32x4 acc[2][4];
#pragma unroll
  for (int i = 0; i < 2; i++)
#pragma unroll
    for (int j = 0; j < 4; j++) acc[i][j] = f32x4{0.f, 0.f, 0.f, 0.f};

  auto stage = [&](int k0, int buf) {
    {  // A: 256 chunks, 1 per thread
      const int row = tid >> 2, c = tid & 3;
      async16(A0 + (size_t)(m0 + row) * 1024 + k0 + c * 8, &LA[buf][wv * 512]);
    }
#pragma unroll
    for (int it = 0; it < 2; it++) {  // B: 512 chunks, 2 per thread
      const int cI = it * 256 + tid;
      const int row = cI >> 2, c = cI & 3;
      async16(W0 + (size_t)(n0 + row) * 1024 + k0 + c * 8,
              &LB[buf][it * 2048 + wv * 512]);
    }
  };

  stage(0, 0);
  for (int t = 0; t < 32; t++) {
    const int buf = t & 1;
    __syncthreads();
    if (t + 1 < 32) stage((t + 1) * 32, buf ^ 1);
    f16x8 af[2], bfr[4];
#pragma unroll
    for (int i = 0; i < 2; i++) af[i] = *(const f16x8*)&LA[buf][(wm * 32 + i * 16 + rl) * 32 + qd * 8];
#pragma unroll
    for (int j = 0; j < 4; j++) bfr[j] = *(const f16x8*)&LB[buf][(wn * 64 + j * 16 + rl) * 32 + qd * 8];
#pragma unroll
    for (int i = 0; i < 2; i++)
#pragma unroll
      for (int j = 0; j < 4; j++) acc[i][j] = mfma_f16(af[i], bfr[j], acc[i][j]);
  }

#pragma unroll
  for (int j = 0; j < 4; j++) {
    const int nn = n0 + wn * 64 + j * 16 + rl;
    const float bj = bias[nn];
#pragma unroll
    for (int i = 0; i < 2; i++) {
      const int mm = m0 + wm * 32 + i * 16 + qd * 4;
#pragma unroll
      for (int r = 0; r < 4; r++)
        out[(size_t)(mm + r) * 1024 + nn] = acc[i][j][r] + bj;
    }
  }
}

// ---------------- launch ----------------
extern "C" void kernel_launch(void* const* d_in, const int* in_sizes, int n_in,
                              void* d_out, int out_size, void* d_ws, size_t ws_size,
                              hipStream_t stream) {
  const float* query = (const float*)d_in[0];
  const float* key   = (const float*)d_in[1];
  const float* value = (const float*)d_in[2];
  const float* Wq = (const float*)d_in[3];
  const float* bq = (const float*)d_in[4];
  const float* Wk = (const float*)d_in[5];
  const float* bk = (const float*)d_in[6];
  const float* Wv = (const float*)d_in[7];
  const float* bv = (const float*)d_in[8];
  const float* Wo = (const float*)d_in[9];
  const float* bo = (const float*)d_in[10];

  // workspace: f16 region 67 MB + f32 partials 34.6 MB
  _Float16* ws = (_Float16*)d_ws;
  _Float16* Xf = ws;                          // 3*E8: query,key,value fp16
  _Float16* Wf = ws + 3 * (size_t)E8;         // 4*M1: Wq,Wk,Wv,Wo fp16
  _Float16* Qh = Wf + 4 * (size_t)M1;         // E8 [B,H,S,HD] (pre-scaled)
  _Float16* Kh = Qh + (size_t)E8;             // E8 [B,H,S,HD]
  _Float16* Vt = Kh + (size_t)E8;             // E8 [B,H,HD,S]
  _Float16* Xa = Vt + (size_t)E8;             // E8 [B,S,D]
  float*    Op = (float*)(Xa + (size_t)E8);   // [2][NROW][64] f32
  float2*   ML = (float2*)(Op + 2 * (size_t)NROW * 64);  // [2][NROW]

  prep_all<<<16384, 256, 0, stream>>>(query, key, value, Wq, Wk, Wv, Wo, Xf, Wf);
  gemm_qkv<<<dim3(8, 32, 3), 256, 0, stream>>>(Xf, Wf, bq, bk, bv, Qh);
  attn_kernel<<<dim3(32, 2, 32), 256, 0, stream>>>(Qh, Kh, Vt, Op, ML);
  merge_kernel<<<4096, 256, 0, stream>>>(Op, ML, Xa);
  gemm_out<<<dim3(8, 64), 256, 0, stream>>>(Xa, Wf + 3 * (size_t)M1, bo, (float*)d_out);
}